// Round 10
// baseline (162.395 us; speedup 1.0000x reference)
//
#include <hip/hip_runtime.h>
#include <cstdint>
#include <cstddef>

typedef unsigned short u16;
typedef unsigned int u32;
typedef __bf16 bf16x8 __attribute__((ext_vector_type(8)));
typedef float f32x4 __attribute__((ext_vector_type(4)));
typedef u16 u16x8 __attribute__((ext_vector_type(8)));
typedef u16 u16x4 __attribute__((ext_vector_type(4)));

#define DD 1024
#define HH 16
#define HDIM 64
#define BB 2
#define SS 2048
#define NQT 32  /* 64-row Q tiles */

__device__ __forceinline__ u16 cvt(float f) {
  __bf16 h = (__bf16)f;            // hw round-to-nearest-even on gfx950
  return __builtin_bit_cast(u16, h);
}
__device__ __forceinline__ f32x4 mfma16(bf16x8 a, bf16x8 b, f32x4 c) {
  return __builtin_amdgcn_mfma_f32_16x16x32_bf16(a, b, c, 0, 0, 0);
}
__device__ __forceinline__ bf16x8 ld_bf8(const u16* p) {
  return __builtin_bit_cast(bf16x8, *(const u16x8*)p);
}
// async global->LDS DMA, 16B per lane. LDS dst must be wave-uniform base + lane*16.
__device__ __forceinline__ void async16(const void* g, void* l) {
  __builtin_amdgcn_global_load_lds(
      (__attribute__((address_space(1))) void*)(uintptr_t)g,
      (__attribute__((address_space(3))) void*)l, 16, 0, 0);
}

// ---------------- fused cast fp32 -> bf16 (x + 4 weights, one launch) ----------------
// R9: two coalesced float4 loads per thread (u and u+256) -> 2x ILP on a
// BW-bound kernel, half the blocks. Region mapping is block-uniform
// (blocks of 512 units align with the 2^18-unit weight regions).
__global__ void cast_all(const float* __restrict__ x, const float* __restrict__ wq,
                         const float* __restrict__ wk, const float* __restrict__ wv,
                         const float* __restrict__ wo, u16* __restrict__ xb,
                         u16* __restrict__ wqb, u16* __restrict__ wkb,
                         u16* __restrict__ wvb, u16* __restrict__ wob) {
  const int t = threadIdx.x;
  const int i = blockIdx.x * 512 + t;      // [0, 2M) float4 units, 2 per thread
  const float* src;
  u16* dst;
  int off;
  if (i < (1 << 20)) {
    src = x; dst = xb; off = i;
  } else {
    int j = i - (1 << 20);
    int w = j >> 18;
    off = j & ((1 << 18) - 1);
    src = (w == 0) ? wq : (w == 1) ? wk : (w == 2) ? wv : wo;
    dst = (w == 0) ? wqb : (w == 1) ? wkb : (w == 2) ? wvb : wob;
  }
  float4 v0 = ((const float4*)src)[off];
  float4 v1 = ((const float4*)src)[off + 256];
  u16x4 o0, o1;
  o0[0] = cvt(v0.x); o0[1] = cvt(v0.y); o0[2] = cvt(v0.z); o0[3] = cvt(v0.w);
  o1[0] = cvt(v1.x); o1[1] = cvt(v1.y); o1[2] = cvt(v1.z); o1[3] = cvt(v1.w);
  *(u16x4*)&dst[(size_t)off * 4] = o0;
  *(u16x4*)&dst[(size_t)(off + 256) * 4] = o1;
}

// ---------------- QKV GEMM + fused RoPE: C[m][e] = sum_k x[m][k] * w[e][k] ----------------
// Q,K out: (B,H,S,HD) bf16, RoPE applied (Q pre-scaled by log2(e)/8);
// V out: TRANSPOSED (B,H,HD,S) bf16
// PIPELINE: 3-buffer ring, prefetch distance 2, counted vmcnt (R6).
// LDS SWIZZLE: chunk c at slot c^((r>>1)&3); linear dest + pre-swizzled global
// source + swizzled read (R7: bank conflicts 3.15M -> 0).
// R8: prefetch DMA issued AFTER the fragment ds_reads (overlaps the lgkm wait).
__global__ __launch_bounds__(256) void gemm_qkv(
    const u16* __restrict__ xb, const u16* __restrict__ wq,
    const u16* __restrict__ wk, const u16* __restrict__ wv,
    u16* __restrict__ Qo, u16* __restrict__ Ko, u16* __restrict__ Vto) {
  __shared__ __align__(16) u16 As[3 * 4096];   // 24 KB (3 x 128x32)
  __shared__ __align__(16) u16 Bs[3 * 4096];   // 24 KB
  const int t = threadIdx.x;
  const int w = t >> 6, l = t & 63, lane16 = l & 15, quad = l >> 4;
  const int m0 = blockIdx.x * 128, n0 = blockIdx.y * 128;
  const u16* wsel = (blockIdx.z == 0) ? wq : (blockIdx.z == 1) ? wk : wv;
  const int m_w = (w >> 1) * 64, n_w = (w & 1) * 64;
  const int srow = t >> 2;
  const int scol = (((t & 3) ^ ((t >> 3) & 3)) * 8);   // pre-swizzled source chunk
  const int rsw = ((lane16 >> 1) & 3);                 // read-side slot XOR key
  const u16* a0 = &xb[(size_t)(m0 + srow) * DD + scol];
  const u16* a1 = &xb[(size_t)(m0 + 64 + srow) * DD + scol];
  const u16* b0 = &wsel[(size_t)(n0 + srow) * DD + scol];
  const u16* b1 = &wsel[(size_t)(n0 + 64 + srow) * DD + scol];

  // ring pointers: aC = buf(kt), aN1 = buf(kt+1), aN2 = buf(kt+2)
  u16 *aC = As, *aN1 = As + 4096, *aN2 = As + 8192;
  u16 *bC = Bs, *bN1 = Bs + 4096, *bN2 = Bs + 8192;

  // prologue: stage loads(0) -> buf0, loads(1) -> buf1 (8 outstanding)
  async16(a0, &aC[t * 8]);        async16(a1, &aC[2048 + t * 8]);
  async16(b0, &bC[t * 8]);        async16(b1, &bC[2048 + t * 8]);
  async16(a0 + 32, &aN1[t * 8]);  async16(a1 + 32, &aN1[2048 + t * 8]);
  async16(b0 + 32, &bN1[t * 8]);  async16(b1 + 32, &bN1[2048 + t * 8]);

  f32x4 acc[4][4] = {};
  for (int kt = 0; kt < 32; ++kt) {
    if (kt < 31) asm volatile("s_waitcnt vmcnt(4)" ::: "memory");
    else         asm volatile("s_waitcnt vmcnt(0)" ::: "memory");
    __builtin_amdgcn_sched_barrier(0);
    __builtin_amdgcn_s_barrier();
    __builtin_amdgcn_sched_barrier(0);
    // fragment ds_reads first: start the lgkm chain immediately post-barrier
    bf16x8 af[4], bfr[4];
#pragma unroll
    for (int mi = 0; mi < 4; ++mi)
      af[mi] = ld_bf8(&aC[(m_w + mi * 16 + lane16) * 32 + ((quad ^ rsw) * 8)]);
#pragma unroll
    for (int ni = 0; ni < 4; ++ni)
      bfr[ni] = ld_bf8(&bC[(n_w + ni * 16 + lane16) * 32 + ((quad ^ rsw) * 8)]);
    // prefetch loads(kt+2) issued under the lgkm wait (WAR safe: buf(kt+2) ==
    // buf(kt-1) mod 3, consumed in compute(kt-1) before barrier(kt))
    if (kt < 30) {
      const int ko = (kt + 2) * 32;
      async16(a0 + ko, &aN2[t * 8]);
      async16(a1 + ko, &aN2[2048 + t * 8]);
      async16(b0 + ko, &bN2[t * 8]);
      async16(b1 + ko, &bN2[2048 + t * 8]);
    }
#pragma unroll
    for (int mi = 0; mi < 4; ++mi)
#pragma unroll
      for (int ni = 0; ni < 4; ++ni)
        acc[mi][ni] = mfma16(af[mi], bfr[ni], acc[mi][ni]);
    // rotate ring
    u16* tp = aC; aC = aN1; aN1 = aN2; aN2 = tp;
    tp = bC; bC = bN1; bN1 = bN2; bN2 = tp;
  }
  if (blockIdx.z == 2) {
    // V^T epilogue: the 4 acc regs are 4 consecutive s -> one u16x4 store per (mi,ni)
#pragma unroll
    for (int mi = 0; mi < 4; ++mi) {
      int mbase = m0 + m_w + mi * 16 + quad * 4;
      int b = mbase >> 11, s0 = mbase & (SS - 1);
#pragma unroll
      for (int ni = 0; ni < 4; ++ni) {
        int e = n0 + n_w + ni * 16 + lane16;
        int h = e >> 6, d = e & 63;
        u16x4 pk;
#pragma unroll
        for (int r = 0; r < 4; ++r) pk[r] = cvt(acc[mi][ni][r]);
        *(u16x4*)&Vto[((size_t)(b * HH + h) * HDIM + d) * SS + s0] = pk;
      }
    }
  } else {
    // fused RoPE epilogue: rotate (d, d+32) pairs on fp32 accumulators.
    u16* osel = (blockIdx.z == 0) ? Qo : Ko;
    const float scale = (blockIdx.z == 0) ? 0.18033688f : 1.0f;  // Q: (1/8)*log2(e)
    float invf[2];
    invf[0] = exp2f((float)lane16 * -0.4152410119f) * 0.15915494309f;        // /(2pi)
    invf[1] = exp2f((float)(16 + lane16) * -0.4152410119f) * 0.15915494309f;
    const int h = (n0 + n_w) >> 6;
#pragma unroll
    for (int mi = 0; mi < 4; ++mi) {
#pragma unroll
      for (int r = 0; r < 4; ++r) {
        int mrow = m0 + m_w + mi * 16 + quad * 4 + r;
        int b = mrow >> 11, s = mrow & (SS - 1);
        size_t rowbase = ((size_t)(b * HH + h) * SS + s) * HDIM;
#pragma unroll
        for (int ni = 0; ni < 2; ++ni) {
          float x1 = acc[mi][ni][r], x2 = acc[mi][ni + 2][r];
          float rv = (float)s * invf[ni];
          rv = rv - floorf(rv);                       // revolutions in [0,1)
          float sn = __builtin_amdgcn_sinf(rv);
          float c  = __builtin_amdgcn_cosf(rv);
          int d = ni * 16 + lane16;
          osel[rowbase + d]      = cvt((x1 * c - x2 * sn) * scale);
          osel[rowbase + d + 32] = cvt((x2 * c + x1 * sn) * scale);
        }
      }
    }
  }
}

// ---------------- Flash attention (causal), transposed-S, double-buffered async ----------
// QBLK=64, KVBLK=64, LDS 40 KB -> 4 blocks/CU. R8: CU-load-balanced y->jj map
// (jj = y<16 ? 31-y : y-16; each CU's 4 resident blocks sum to a constant load).
// R9: prefetch DMA for tile kt+1 issued AFTER the S^T fragment reads + MFMAs.
__global__ __launch_bounds__(256, 4) void attn_k(const u16* __restrict__ Qb,
                                                 const u16* __restrict__ Kb,
                                                 const u16* __restrict__ Vt,
                                                 u16* __restrict__ AO) {
  __shared__ __align__(16) u16 KsF[2][64 * 64]; // 16 KB; chunk p: r=p>>3, gc=(p&7)^(r&7)
  __shared__ __align__(16) u16 VtL[2][64 * 64]; // 16 KB; chunk p: d=p>>3, gq=(p&7)^(d&7)
  __shared__ __align__(16) u16 Ps[4][16 * 64];  //  8 KB; per-wave P, chunk c^(q&7)
  const int t = threadIdx.x;
  const int w = t >> 6, l = t & 63, lane16 = l & 15, quad = l >> 4;
  const int bh = blockIdx.x;
  const int y = (int)blockIdx.y;
  const int jj = (y < 16) ? (31 - y) : (y - 16);   // balanced bijection on [0,32)
  const size_t base = (size_t)bh * SS * HDIM;
  const u16* Qp = Qb + base;
  const int b = bh >> 4, h = bh & 15;

  const int q0 = jj * 64;
  const int qrow = q0 + w * 16 + lane16;
  bf16x8 qf0 = ld_bf8(&Qp[(size_t)qrow * 64 + quad * 8]);
  bf16x8 qf1 = ld_bf8(&Qp[(size_t)qrow * 64 + 32 + quad * 8]);

  // all-ones A fragment (bf16 1.0 = 0x3F80)
  u16x8 onesu;
#pragma unroll
  for (int i = 0; i < 8; ++i) onesu[i] = 0x3F80;
  const bf16x8 ones = __builtin_bit_cast(bf16x8, onesu);

  f32x4 o[4] = {};    // O^T tiles: col=q=lane16, rows d = nd*16 + quad*4 + r
  f32x4 lacc = {};    // every reg = l[q=lane16]
  const f32x4 zf = {};  // shared zero C-operand (avoids per-iter v_mov re-init)

  // DMA source pointers (K advances 64*64 elems/tile, V^T 64 elems/tile)
  const u16* kptr[2];
  const u16* vptr[2];
#pragma unroll
  for (int i = 0; i < 2; ++i) {
    int p = i * 256 + t;
    int r = p >> 3;
    int c = (p & 7) ^ (r & 7);
    kptr[i] = Kb + base + (size_t)r * 64 + c * 8;
    int d = p >> 3;
    int q = (p & 7) ^ (d & 7);
    vptr[i] = Vt + base + (size_t)d * SS + q * 8;
  }

  // ---- prologue: stage tile 0 into buffer 0 ----
#pragma unroll
  for (int i = 0; i < 2; ++i) {
    async16(kptr[i], &KsF[0][(i * 256 + t) * 8]);
    kptr[i] += 64 * 64;
    async16(vptr[i], &VtL[0][(i * 256 + t) * 8]);
    vptr[i] += 64;
  }

  u16* Pw = Ps[w];
  const int ktmax = jj;
  for (int kt = 0; kt <= ktmax; ++kt) {
    __syncthreads();   // drains tile-kt DMA (issued a full compute ago, except kt=0)
    const u16* Kc = KsF[kt & 1];
    const u16* Vc = VtL[kt & 1];
    const int kv0 = kt * 64;
    // ---- S^T = K Q^T over 64 kv rows (per-lane col q = qrow) ----
    f32x4 st[4];
    __builtin_amdgcn_s_setprio(1);
#pragma unroll
    for (int nc = 0; nc < 4; ++nc) {
      int rr = nc * 16 + lane16;
      int p0 = rr * 8 + (quad ^ (rr & 7));
      int p1 = rr * 8 + ((4 + quad) ^ (rr & 7));
      f32x4 a = mfma16(ld_bf8(&Kc[p0 * 8]), qf0, zf);
      a = mfma16(ld_bf8(&Kc[p1 * 8]), qf1, a);
      st[nc] = a;
    }
    __builtin_amdgcn_s_setprio(0);
    // ---- prefetch tile kt+1 (R9: issued after the S^T lgkm chain; writes the
    // OTHER buffer, whose prior readers all retired before barrier(kt)) ----
    if (kt < ktmax) {
      const int nb = (kt + 1) & 1;
#pragma unroll
      for (int i = 0; i < 2; ++i) {
        async16(kptr[i], &KsF[nb][(i * 256 + t) * 8]);
        kptr[i] += 64 * 64;
        async16(vptr[i], &VtL[nb][(i * 256 + t) * 8]);
        vptr[i] += 64;
      }
    }
    // ---- causal mask on last iteration (kv on C rows, q on lanes) ----
    if (kt == ktmax) {
#pragma unroll
      for (int nc = 0; nc < 4; ++nc) {
        int kvb = kv0 + nc * 16 + quad * 4;
#pragma unroll
        for (int r = 0; r < 4; ++r)
          if (kvb + r > qrow) st[nc][r] = -3.0e38f;
      }
    }
    // ---- softmax numerator: p = 2^sc (bias cancels in normalization) ----
#pragma unroll
    for (int nc = 0; nc < 4; ++nc)
#pragma unroll
      for (int r = 0; r < 4; ++r) st[nc][r] = __builtin_amdgcn_exp2f(st[nc][r]);
    // ---- P -> per-wave swizzled LDS (4 b64 writes, full 64-kv width) ----
#pragma unroll
    for (int nc = 0; nc < 4; ++nc) {
      u16x4 pk;
#pragma unroll
      for (int r = 0; r < 4; ++r) pk[r] = cvt(st[nc][r]);
      int addr = lane16 * 64 + (((nc * 2 + (quad >> 1)) ^ (lane16 & 7)) * 8) + (quad & 1) * 4;
      *(u16x4*)&Pw[addr] = pk;
    }
    // ---- read 2 B-frags, accumulate O^T and l ----
    __builtin_amdgcn_s_setprio(1);
#pragma unroll
    for (int G = 0; G < 2; ++G) {
      int gc = ((G * 4 + quad) ^ (lane16 & 7)) * 8;
      bf16x8 pf = ld_bf8(&Pw[lane16 * 64 + gc]);
      lacc = mfma16(ones, pf, lacc);
#pragma unroll
      for (int nd = 0; nd < 4; ++nd) {
        int d = nd * 16 + lane16;
        bf16x8 bv = ld_bf8(&Vc[(size_t)d * 64 + gc]);
        o[nd] = mfma16(bv, pf, o[nd]);
      }
    }
    __builtin_amdgcn_s_setprio(0);
  }
  // ---- epilogue: O^T col q=lane16; d = nd*16 + quad*4 + r (u16x4 stores) ----
  const float inv = 1.0f / lacc[0];
  const size_t rowb = (size_t)(b * SS + qrow) * DD + h * HDIM + quad * 4;
#pragma unroll
  for (int nd = 0; nd < 4; ++nd) {
    u16x4 pk;
#pragma unroll
    for (int r = 0; r < 4; ++r) pk[r] = cvt(o[nd][r] * inv);
    *(u16x4*)&AO[rowb + nd * 16] = pk;
  }
}

// ---------------- output GEMM: out[m][e] = sum_k AO[m][k] * wo[e][k] (fp32 out) -------
// R10: RETILED 128x64 -> 64x64, grid (64,16)=1024 -> 4 blocks/CU (was 2).
// gemm_out was the lowest-TLP kernel in the pipeline (grid 512 = 2/CU) while
// latency-bound like everything else; occupancy is the session's only
// consistently-paying lever. Per wave: 32x32 output (2x2 frags, 4 MFMA/iter),
// 2 staging async16/thread/iter (counted vmcnt(2)). Same verified 3-ring +
// distance-2 prefetch + chunk-XOR swizzle schedule (row bases stay multiples
// of 16 so the (r>>1)&3 read key is unchanged). LDS 24 KB, VGPR drops.
__global__ __launch_bounds__(256) void gemm_out(const u16* __restrict__ A, const u16* __restrict__ W,
                                                float* __restrict__ out) {
  __shared__ __align__(16) u16 As[3 * 2048];  // 12 KB (3 x 64x32)
  __shared__ __align__(16) u16 Bs[3 * 2048];  // 12 KB
  const int t = threadIdx.x;
  const int w = t >> 6, l = t & 63, lane16 = l & 15, quad = l >> 4;
  const int m0 = blockIdx.x * 64, n0 = blockIdx.y * 64;
  const int m_w = (w >> 1) * 32, n_w = (w & 1) * 32;
  const int srow = t >> 2;                             // 0..63
  const int scol = (((t & 3) ^ ((t >> 3) & 3)) * 8);   // pre-swizzled source chunk
  const int rsw = ((lane16 >> 1) & 3);                 // read-side slot XOR key
  const u16* a0 = &A[(size_t)(m0 + srow) * DD + scol];
  const u16* b0 = &W[(size_t)(n0 + srow) * DD + scol];

  u16 *aC = As, *aN1 = As + 2048, *aN2 = As + 4096;
  u16 *bC = Bs, *bN1 = Bs + 2048, *bN2 = Bs + 4096;

  // prologue: stage loads(0) -> buf0, loads(1) -> buf1 (4 outstanding)
  async16(a0, &aC[t * 8]);
  async16(b0, &bC[t * 8]);
  async16(a0 + 32, &aN1[t * 8]);
  async16(b0 + 32, &bN1[t * 8]);

  f32x4 acc[2][2] = {};
  for (int kt = 0; kt < 32; ++kt) {
    if (kt < 31) asm volatile("s_waitcnt vmcnt(2)" ::: "memory");
    else         asm volatile("s_waitcnt vmcnt(0)" ::: "memory");
    __builtin_amdgcn_sched_barrier(0);
    __builtin_amdgcn_s_barrier();
    __builtin_amdgcn_sched_barrier(0);
    bf16x8 af[2], bfr[2];
#pragma unroll
    for (int mi = 0; mi < 2; ++mi)
      af[mi] = ld_bf8(&aC[(m_w + mi * 16 + lane16) * 32 + ((quad ^ rsw) * 8)]);
#pragma unroll
    for (int ni = 0; ni < 2; ++ni)
      bfr[ni] = ld_bf8(&bC[(n_w + ni * 16 + lane16) * 32 + ((quad ^ rsw) * 8)]);
    if (kt < 30) {
      const int ko = (kt + 2) * 32;
      async16(a0 + ko, &aN2[t * 8]);
      async16(b0 + ko, &bN2[t * 8]);
    }
#pragma unroll
    for (int mi = 0; mi < 2; ++mi)
#pragma unroll
      for (int ni = 0; ni < 2; ++ni)
        acc[mi][ni] = mfma16(af[mi], bfr[ni], acc[mi][ni]);
    u16* tp = aC; aC = aN1; aN1 = aN2; aN2 = tp;
    tp = bC; bC = bN1; bN1 = bN2; bN2 = tp;
  }
#pragma unroll
  for (int mi = 0; mi < 2; ++mi) {
#pragma unroll
    for (int r = 0; r < 4; ++r) {
      int mrow = m0 + m_w + mi * 16 + quad * 4 + r;
#pragma unroll
      for (int ni = 0; ni < 2; ++ni) {
        int e = n0 + n_w + ni * 16 + lane16;
        out[(size_t)mrow * DD + e] = acc[mi][ni][r];
      }
    }
  }
}

extern "C" void kernel_launch(void* const* d_in, const int* in_sizes, int n_in,
                              void* d_out, int out_size, void* d_ws, size_t ws_size,
                              hipStream_t stream) {
  const float* x  = (const float*)d_in[0];
  const float* wq = (const float*)d_in[1];
  const float* wk = (const float*)d_in[2];
  const float* wv = (const float*)d_in[3];
  const float* wo = (const float*)d_in[4];
  float* out = (float*)d_out;
  char* ws = (char*)d_ws;

  u16* xb  = (u16*)(ws + (size_t)0);
  u16* wqb = (u16*)(ws + ((size_t)8  << 20));
  u16* wkb = (u16*)(ws + ((size_t)10 << 20));
  u16* wvb = (u16*)(ws + ((size_t)12 << 20));
  u16* wob = (u16*)(ws + ((size_t)14 << 20));
  u16* Qb  = (u16*)(ws + ((size_t)16 << 20));
  u16* Kb  = (u16*)(ws + ((size_t)24 << 20));
  u16* Vtg = (u16*)(ws + ((size_t)32 << 20));
  u16* AO  = (u16*)(ws + ((size_t)40 << 20));

  cast_all<<<4096, 256, 0, stream>>>(x, wq, wk, wv, wo, xb, wqb, wkb, wvb, wob);
  gemm_qkv<<<dim3(32, 8, 3), 256, 0, stream>>>(xb, wqb, wkb, wvb, Qb, Kb, Vtg);
  attn_k<<<dim3(32, 32), 256, 0, stream>>>(Qb, Kb, Vtg, AO);
  gemm_out<<<dim3(64, 16), 256, 0, stream>>>(AO, wob, out);
}

// Round 11
// 160.954 us; speedup vs baseline: 1.0090x; 1.0090x over previous
//
#include <hip/hip_runtime.h>
#include <cstdint>
#include <cstddef>

typedef unsigned short u16;
typedef unsigned int u32;
typedef __bf16 bf16x8 __attribute__((ext_vector_type(8)));
typedef float f32x4 __attribute__((ext_vector_type(4)));
typedef u16 u16x8 __attribute__((ext_vector_type(8)));
typedef u16 u16x4 __attribute__((ext_vector_type(4)));

#define DD 1024
#define HH 16
#define HDIM 64
#define BB 2
#define SS 2048
#define NQT 32  /* 64-row Q tiles */

__device__ __forceinline__ u16 cvt(float f) {
  __bf16 h = (__bf16)f;            // hw round-to-nearest-even on gfx950
  return __builtin_bit_cast(u16, h);
}
__device__ __forceinline__ f32x4 mfma16(bf16x8 a, bf16x8 b, f32x4 c) {
  return __builtin_amdgcn_mfma_f32_16x16x32_bf16(a, b, c, 0, 0, 0);
}
__device__ __forceinline__ bf16x8 ld_bf8(const u16* p) {
  return __builtin_bit_cast(bf16x8, *(const u16x8*)p);
}
// async global->LDS DMA, 16B per lane. LDS dst must be wave-uniform base + lane*16.
__device__ __forceinline__ void async16(const void* g, void* l) {
  __builtin_amdgcn_global_load_lds(
      (__attribute__((address_space(1))) void*)(uintptr_t)g,
      (__attribute__((address_space(3))) void*)l, 16, 0, 0);
}

// ---------------- fused cast fp32 -> bf16 (x + 4 weights, one launch) ----------------
// R11: four coalesced float4 loads per thread (off +0/+256/+512/+768) -> 4x MLP
// on the purely BW-bound kernel; grid 2048. Block's 1024-unit window stays in
// one region (region sizes are multiples of 1024 units).
__global__ void cast_all(const float* __restrict__ x, const float* __restrict__ wq,
                         const float* __restrict__ wk, const float* __restrict__ wv,
                         const float* __restrict__ wo, u16* __restrict__ xb,
                         u16* __restrict__ wqb, u16* __restrict__ wkb,
                         u16* __restrict__ wvb, u16* __restrict__ wob) {
  const int t = threadIdx.x;
  const int i = blockIdx.x * 1024 + t;     // [0, 2M) float4 units, 4 per thread
  const float* src;
  u16* dst;
  int off;
  if (i < (1 << 20)) {
    src = x; dst = xb; off = i;
  } else {
    int j = i - (1 << 20);
    int w = j >> 18;
    off = j & ((1 << 18) - 1);
    src = (w == 0) ? wq : (w == 1) ? wk : (w == 2) ? wv : wo;
    dst = (w == 0) ? wqb : (w == 1) ? wkb : (w == 2) ? wvb : wob;
  }
  float4 v0 = ((const float4*)src)[off];
  float4 v1 = ((const float4*)src)[off + 256];
  float4 v2 = ((const float4*)src)[off + 512];
  float4 v3 = ((const float4*)src)[off + 768];
  u16x4 o0, o1, o2, o3;
  o0[0] = cvt(v0.x); o0[1] = cvt(v0.y); o0[2] = cvt(v0.z); o0[3] = cvt(v0.w);
  o1[0] = cvt(v1.x); o1[1] = cvt(v1.y); o1[2] = cvt(v1.z); o1[3] = cvt(v1.w);
  o2[0] = cvt(v2.x); o2[1] = cvt(v2.y); o2[2] = cvt(v2.z); o2[3] = cvt(v2.w);
  o3[0] = cvt(v3.x); o3[1] = cvt(v3.y); o3[2] = cvt(v3.z); o3[3] = cvt(v3.w);
  *(u16x4*)&dst[(size_t)off * 4] = o0;
  *(u16x4*)&dst[(size_t)(off + 256) * 4] = o1;
  *(u16x4*)&dst[(size_t)(off + 512) * 4] = o2;
  *(u16x4*)&dst[(size_t)(off + 768) * 4] = o3;
}

// ---------------- QKV GEMM + fused RoPE: C[m][e] = sum_k x[m][k] * w[e][k] ----------------
// Q,K out: (B,H,S,HD) bf16, RoPE applied (Q pre-scaled by log2(e)/8);
// V out: TRANSPOSED (B,H,HD,S) bf16
// PIPELINE: 3-buffer ring, prefetch distance 2, counted vmcnt (R6).
// LDS SWIZZLE: chunk c at slot c^((r>>1)&3); linear dest + pre-swizzled global
// source + swizzled read (R7: bank conflicts 3.15M -> 0).
// R8: prefetch DMA issued AFTER the fragment ds_reads (overlaps the lgkm wait).
__global__ __launch_bounds__(256) void gemm_qkv(
    const u16* __restrict__ xb, const u16* __restrict__ wq,
    const u16* __restrict__ wk, const u16* __restrict__ wv,
    u16* __restrict__ Qo, u16* __restrict__ Ko, u16* __restrict__ Vto) {
  __shared__ __align__(16) u16 As[3 * 4096];   // 24 KB (3 x 128x32)
  __shared__ __align__(16) u16 Bs[3 * 4096];   // 24 KB
  const int t = threadIdx.x;
  const int w = t >> 6, l = t & 63, lane16 = l & 15, quad = l >> 4;
  const int m0 = blockIdx.x * 128, n0 = blockIdx.y * 128;
  const u16* wsel = (blockIdx.z == 0) ? wq : (blockIdx.z == 1) ? wk : wv;
  const int m_w = (w >> 1) * 64, n_w = (w & 1) * 64;
  const int srow = t >> 2;
  const int scol = (((t & 3) ^ ((t >> 3) & 3)) * 8);   // pre-swizzled source chunk
  const int rsw = ((lane16 >> 1) & 3);                 // read-side slot XOR key
  const u16* a0 = &xb[(size_t)(m0 + srow) * DD + scol];
  const u16* a1 = &xb[(size_t)(m0 + 64 + srow) * DD + scol];
  const u16* b0 = &wsel[(size_t)(n0 + srow) * DD + scol];
  const u16* b1 = &wsel[(size_t)(n0 + 64 + srow) * DD + scol];

  // ring pointers: aC = buf(kt), aN1 = buf(kt+1), aN2 = buf(kt+2)
  u16 *aC = As, *aN1 = As + 4096, *aN2 = As + 8192;
  u16 *bC = Bs, *bN1 = Bs + 4096, *bN2 = Bs + 8192;

  // prologue: stage loads(0) -> buf0, loads(1) -> buf1 (8 outstanding)
  async16(a0, &aC[t * 8]);        async16(a1, &aC[2048 + t * 8]);
  async16(b0, &bC[t * 8]);        async16(b1, &bC[2048 + t * 8]);
  async16(a0 + 32, &aN1[t * 8]);  async16(a1 + 32, &aN1[2048 + t * 8]);
  async16(b0 + 32, &bN1[t * 8]);  async16(b1 + 32, &bN1[2048 + t * 8]);

  f32x4 acc[4][4] = {};
  for (int kt = 0; kt < 32; ++kt) {
    if (kt < 31) asm volatile("s_waitcnt vmcnt(4)" ::: "memory");
    else         asm volatile("s_waitcnt vmcnt(0)" ::: "memory");
    __builtin_amdgcn_sched_barrier(0);
    __builtin_amdgcn_s_barrier();
    __builtin_amdgcn_sched_barrier(0);
    // fragment ds_reads first: start the lgkm chain immediately post-barrier
    bf16x8 af[4], bfr[4];
#pragma unroll
    for (int mi = 0; mi < 4; ++mi)
      af[mi] = ld_bf8(&aC[(m_w + mi * 16 + lane16) * 32 + ((quad ^ rsw) * 8)]);
#pragma unroll
    for (int ni = 0; ni < 4; ++ni)
      bfr[ni] = ld_bf8(&bC[(n_w + ni * 16 + lane16) * 32 + ((quad ^ rsw) * 8)]);
    // prefetch loads(kt+2) issued under the lgkm wait (WAR safe: buf(kt+2) ==
    // buf(kt-1) mod 3, consumed in compute(kt-1) before barrier(kt))
    if (kt < 30) {
      const int ko = (kt + 2) * 32;
      async16(a0 + ko, &aN2[t * 8]);
      async16(a1 + ko, &aN2[2048 + t * 8]);
      async16(b0 + ko, &bN2[t * 8]);
      async16(b1 + ko, &bN2[2048 + t * 8]);
    }
#pragma unroll
    for (int mi = 0; mi < 4; ++mi)
#pragma unroll
      for (int ni = 0; ni < 4; ++ni)
        acc[mi][ni] = mfma16(af[mi], bfr[ni], acc[mi][ni]);
    // rotate ring
    u16* tp = aC; aC = aN1; aN1 = aN2; aN2 = tp;
    tp = bC; bC = bN1; bN1 = bN2; bN2 = tp;
  }
  if (blockIdx.z == 2) {
    // V^T epilogue: the 4 acc regs are 4 consecutive s -> one u16x4 store per (mi,ni)
#pragma unroll
    for (int mi = 0; mi < 4; ++mi) {
      int mbase = m0 + m_w + mi * 16 + quad * 4;
      int b = mbase >> 11, s0 = mbase & (SS - 1);
#pragma unroll
      for (int ni = 0; ni < 4; ++ni) {
        int e = n0 + n_w + ni * 16 + lane16;
        int h = e >> 6, d = e & 63;
        u16x4 pk;
#pragma unroll
        for (int r = 0; r < 4; ++r) pk[r] = cvt(acc[mi][ni][r]);
        *(u16x4*)&Vto[((size_t)(b * HH + h) * HDIM + d) * SS + s0] = pk;
      }
    }
  } else {
    // fused RoPE epilogue: rotate (d, d+32) pairs on fp32 accumulators.
    u16* osel = (blockIdx.z == 0) ? Qo : Ko;
    const float scale = (blockIdx.z == 0) ? 0.18033688f : 1.0f;  // Q: (1/8)*log2(e)
    float invf[2];
    invf[0] = exp2f((float)lane16 * -0.4152410119f) * 0.15915494309f;        // /(2pi)
    invf[1] = exp2f((float)(16 + lane16) * -0.4152410119f) * 0.15915494309f;
    const int h = (n0 + n_w) >> 6;
#pragma unroll
    for (int mi = 0; mi < 4; ++mi) {
#pragma unroll
      for (int r = 0; r < 4; ++r) {
        int mrow = m0 + m_w + mi * 16 + quad * 4 + r;
        int b = mrow >> 11, s = mrow & (SS - 1);
        size_t rowbase = ((size_t)(b * HH + h) * SS + s) * HDIM;
#pragma unroll
        for (int ni = 0; ni < 2; ++ni) {
          float x1 = acc[mi][ni][r], x2 = acc[mi][ni + 2][r];
          float rv = (float)s * invf[ni];
          rv = rv - floorf(rv);                       // revolutions in [0,1)
          float sn = __builtin_amdgcn_sinf(rv);
          float c  = __builtin_amdgcn_cosf(rv);
          int d = ni * 16 + lane16;
          osel[rowbase + d]      = cvt((x1 * c - x2 * sn) * scale);
          osel[rowbase + d + 32] = cvt((x2 * c + x1 * sn) * scale);
        }
      }
    }
  }
}

// ---------------- Flash attention (causal), transposed-S, double-buffered async ----------
// QBLK=64, KVBLK=64, LDS 40 KB -> 4 blocks/CU. R8: CU-load-balanced y->jj map
// (jj = y<16 ? 31-y : y-16; each CU's 4 resident blocks sum to a constant load).
// R9: prefetch DMA for tile kt+1 issued AFTER the S^T fragment reads + MFMAs.
__global__ __launch_bounds__(256, 4) void attn_k(const u16* __restrict__ Qb,
                                                 const u16* __restrict__ Kb,
                                                 const u16* __restrict__ Vt,
                                                 u16* __restrict__ AO) {
  __shared__ __align__(16) u16 KsF[2][64 * 64]; // 16 KB; chunk p: r=p>>3, gc=(p&7)^(r&7)
  __shared__ __align__(16) u16 VtL[2][64 * 64]; // 16 KB; chunk p: d=p>>3, gq=(p&7)^(d&7)
  __shared__ __align__(16) u16 Ps[4][16 * 64];  //  8 KB; per-wave P, chunk c^(q&7)
  const int t = threadIdx.x;
  const int w = t >> 6, l = t & 63, lane16 = l & 15, quad = l >> 4;
  const int bh = blockIdx.x;
  const int y = (int)blockIdx.y;
  const int jj = (y < 16) ? (31 - y) : (y - 16);   // balanced bijection on [0,32)
  const size_t base = (size_t)bh * SS * HDIM;
  const u16* Qp = Qb + base;
  const int b = bh >> 4, h = bh & 15;

  const int q0 = jj * 64;
  const int qrow = q0 + w * 16 + lane16;
  bf16x8 qf0 = ld_bf8(&Qp[(size_t)qrow * 64 + quad * 8]);
  bf16x8 qf1 = ld_bf8(&Qp[(size_t)qrow * 64 + 32 + quad * 8]);

  // all-ones A fragment (bf16 1.0 = 0x3F80)
  u16x8 onesu;
#pragma unroll
  for (int i = 0; i < 8; ++i) onesu[i] = 0x3F80;
  const bf16x8 ones = __builtin_bit_cast(bf16x8, onesu);

  f32x4 o[4] = {};    // O^T tiles: col=q=lane16, rows d = nd*16 + quad*4 + r
  f32x4 lacc = {};    // every reg = l[q=lane16]
  const f32x4 zf = {};  // shared zero C-operand (avoids per-iter v_mov re-init)

  // DMA source pointers (K advances 64*64 elems/tile, V^T 64 elems/tile)
  const u16* kptr[2];
  const u16* vptr[2];
#pragma unroll
  for (int i = 0; i < 2; ++i) {
    int p = i * 256 + t;
    int r = p >> 3;
    int c = (p & 7) ^ (r & 7);
    kptr[i] = Kb + base + (size_t)r * 64 + c * 8;
    int d = p >> 3;
    int q = (p & 7) ^ (d & 7);
    vptr[i] = Vt + base + (size_t)d * SS + q * 8;
  }

  // ---- prologue: stage tile 0 into buffer 0 ----
#pragma unroll
  for (int i = 0; i < 2; ++i) {
    async16(kptr[i], &KsF[0][(i * 256 + t) * 8]);
    kptr[i] += 64 * 64;
    async16(vptr[i], &VtL[0][(i * 256 + t) * 8]);
    vptr[i] += 64;
  }

  u16* Pw = Ps[w];
  const int ktmax = jj;
  for (int kt = 0; kt <= ktmax; ++kt) {
    __syncthreads();   // drains tile-kt DMA (issued a full compute ago, except kt=0)
    const u16* Kc = KsF[kt & 1];
    const u16* Vc = VtL[kt & 1];
    const int kv0 = kt * 64;
    // ---- S^T = K Q^T over 64 kv rows (per-lane col q = qrow) ----
    f32x4 st[4];
    __builtin_amdgcn_s_setprio(1);
#pragma unroll
    for (int nc = 0; nc < 4; ++nc) {
      int rr = nc * 16 + lane16;
      int p0 = rr * 8 + (quad ^ (rr & 7));
      int p1 = rr * 8 + ((4 + quad) ^ (rr & 7));
      f32x4 a = mfma16(ld_bf8(&Kc[p0 * 8]), qf0, zf);
      a = mfma16(ld_bf8(&Kc[p1 * 8]), qf1, a);
      st[nc] = a;
    }
    __builtin_amdgcn_s_setprio(0);
    // ---- prefetch tile kt+1 (R9: issued after the S^T lgkm chain; writes the
    // OTHER buffer, whose prior readers all retired before barrier(kt)) ----
    if (kt < ktmax) {
      const int nb = (kt + 1) & 1;
#pragma unroll
      for (int i = 0; i < 2; ++i) {
        async16(kptr[i], &KsF[nb][(i * 256 + t) * 8]);
        kptr[i] += 64 * 64;
        async16(vptr[i], &VtL[nb][(i * 256 + t) * 8]);
        vptr[i] += 64;
      }
    }
    // ---- causal mask on last iteration (kv on C rows, q on lanes) ----
    if (kt == ktmax) {
#pragma unroll
      for (int nc = 0; nc < 4; ++nc) {
        int kvb = kv0 + nc * 16 + quad * 4;
#pragma unroll
        for (int r = 0; r < 4; ++r)
          if (kvb + r > qrow) st[nc][r] = -3.0e38f;
      }
    }
    // ---- softmax numerator: p = 2^sc (bias cancels in normalization) ----
#pragma unroll
    for (int nc = 0; nc < 4; ++nc)
#pragma unroll
      for (int r = 0; r < 4; ++r) st[nc][r] = __builtin_amdgcn_exp2f(st[nc][r]);
    // ---- P -> per-wave swizzled LDS (4 b64 writes, full 64-kv width) ----
#pragma unroll
    for (int nc = 0; nc < 4; ++nc) {
      u16x4 pk;
#pragma unroll
      for (int r = 0; r < 4; ++r) pk[r] = cvt(st[nc][r]);
      int addr = lane16 * 64 + (((nc * 2 + (quad >> 1)) ^ (lane16 & 7)) * 8) + (quad & 1) * 4;
      *(u16x4*)&Pw[addr] = pk;
    }
    // ---- read 2 B-frags, accumulate O^T and l ----
    __builtin_amdgcn_s_setprio(1);
#pragma unroll
    for (int G = 0; G < 2; ++G) {
      int gc = ((G * 4 + quad) ^ (lane16 & 7)) * 8;
      bf16x8 pf = ld_bf8(&Pw[lane16 * 64 + gc]);
      lacc = mfma16(ones, pf, lacc);
#pragma unroll
      for (int nd = 0; nd < 4; ++nd) {
        int d = nd * 16 + lane16;
        bf16x8 bv = ld_bf8(&Vc[(size_t)d * 64 + gc]);
        o[nd] = mfma16(bv, pf, o[nd]);
      }
    }
    __builtin_amdgcn_s_setprio(0);
  }
  // ---- epilogue: O^T col q=lane16; d = nd*16 + quad*4 + r (u16x4 stores) ----
  const float inv = 1.0f / lacc[0];
  const size_t rowb = (size_t)(b * SS + qrow) * DD + h * HDIM + quad * 4;
#pragma unroll
  for (int nd = 0; nd < 4; ++nd) {
    u16x4 pk;
#pragma unroll
    for (int r = 0; r < 4; ++r) pk[r] = cvt(o[nd][r] * inv);
    *(u16x4*)&AO[rowb + nd * 16] = pk;
  }
}

// ---------------- output GEMM: out[m][e] = sum_k AO[m][k] * wo[e][k] (fp32 out) -------
// R11: REVERTED to the best-measured R9 config (128x64 tiles, grid 512,
// counted-vmcnt 3-ring, chunk swizzle, prefetch-after-ds_reads). R10's 64x64
// retile read +1.0us total -> occupancy-via-smaller-tile is neutral-to-negative
// on lockstep GEMMs (matches R4's attn lesson).
__global__ __launch_bounds__(256) void gemm_out(const u16* __restrict__ A, const u16* __restrict__ W,
                                                float* __restrict__ out) {
  __shared__ __align__(16) u16 As[3 * 4096];  // 24 KB
  __shared__ __align__(16) u16 Bs[3 * 2048];  // 12 KB
  const int t = threadIdx.x;
  const int w = t >> 6, l = t & 63, lane16 = l & 15, quad = l >> 4;
  const int m0 = blockIdx.x * 128, n0 = blockIdx.y * 64;
  const int m_w = (w >> 1) * 64, n_w = (w & 1) * 32;
  const int srow = t >> 2;
  const int scol = (((t & 3) ^ ((t >> 3) & 3)) * 8);   // pre-swizzled source chunk
  const int rsw = ((lane16 >> 1) & 3);                 // read-side slot XOR key
  const u16* a0 = &A[(size_t)(m0 + srow) * DD + scol];
  const u16* a1 = &A[(size_t)(m0 + 64 + srow) * DD + scol];
  const u16* b0 = &W[(size_t)(n0 + srow) * DD + scol];

  u16 *aC = As, *aN1 = As + 4096, *aN2 = As + 8192;
  u16 *bC = Bs, *bN1 = Bs + 2048, *bN2 = Bs + 4096;

  // prologue: stage loads(0) -> buf0, loads(1) -> buf1
  async16(a0, &aC[t * 8]);        async16(a1, &aC[2048 + t * 8]);
  async16(b0, &bC[t * 8]);
  async16(a0 + 32, &aN1[t * 8]);  async16(a1 + 32, &aN1[2048 + t * 8]);
  async16(b0 + 32, &bN1[t * 8]);

  f32x4 acc[4][2] = {};
  for (int kt = 0; kt < 32; ++kt) {
    if (kt < 31) asm volatile("s_waitcnt vmcnt(3)" ::: "memory");
    else         asm volatile("s_waitcnt vmcnt(0)" ::: "memory");
    __builtin_amdgcn_sched_barrier(0);
    __builtin_amdgcn_s_barrier();
    __builtin_amdgcn_sched_barrier(0);
    bf16x8 af[4], bfr[2];
#pragma unroll
    for (int mi = 0; mi < 4; ++mi)
      af[mi] = ld_bf8(&aC[(m_w + mi * 16 + lane16) * 32 + ((quad ^ rsw) * 8)]);
#pragma unroll
    for (int ni = 0; ni < 2; ++ni)
      bfr[ni] = ld_bf8(&bC[(n_w + ni * 16 + lane16) * 32 + ((quad ^ rsw) * 8)]);
    if (kt < 30) {
      const int ko = (kt + 2) * 32;
      async16(a0 + ko, &aN2[t * 8]);
      async16(a1 + ko, &aN2[2048 + t * 8]);
      async16(b0 + ko, &bN2[t * 8]);
    }
#pragma unroll
    for (int mi = 0; mi < 4; ++mi)
#pragma unroll
      for (int ni = 0; ni < 2; ++ni)
        acc[mi][ni] = mfma16(af[mi], bfr[ni], acc[mi][ni]);
    u16* tp = aC; aC = aN1; aN1 = aN2; aN2 = tp;
    tp = bC; bC = bN1; bN1 = bN2; bN2 = tp;
  }
#pragma unroll
  for (int mi = 0; mi < 4; ++mi) {
#pragma unroll
    for (int r = 0; r < 4; ++r) {
      int mrow = m0 + m_w + mi * 16 + quad * 4 + r;
#pragma unroll
      for (int ni = 0; ni < 2; ++ni) {
        int e = n0 + n_w + ni * 16 + lane16;
        out[(size_t)mrow * DD + e] = acc[mi][ni][r];
      }
    }
  }
}

extern "C" void kernel_launch(void* const* d_in, const int* in_sizes, int n_in,
                              void* d_out, int out_size, void* d_ws, size_t ws_size,
                              hipStream_t stream) {
  const float* x  = (const float*)d_in[0];
  const float* wq = (const float*)d_in[1];
  const float* wk = (const float*)d_in[2];
  const float* wv = (const float*)d_in[3];
  const float* wo = (const float*)d_in[4];
  float* out = (float*)d_out;
  char* ws = (char*)d_ws;

  u16* xb  = (u16*)(ws + (size_t)0);
  u16* wqb = (u16*)(ws + ((size_t)8  << 20));
  u16* wkb = (u16*)(ws + ((size_t)10 << 20));
  u16* wvb = (u16*)(ws + ((size_t)12 << 20));
  u16* wob = (u16*)(ws + ((size_t)14 << 20));
  u16* Qb  = (u16*)(ws + ((size_t)16 << 20));
  u16* Kb  = (u16*)(ws + ((size_t)24 << 20));
  u16* Vtg = (u16*)(ws + ((size_t)32 << 20));
  u16* AO  = (u16*)(ws + ((size_t)40 << 20));

  cast_all<<<2048, 256, 0, stream>>>(x, wq, wk, wv, wo, xb, wqb, wkb, wvb, wob);
  gemm_qkv<<<dim3(32, 8, 3), 256, 0, stream>>>(xb, wqb, wkb, wvb, Qb, Kb, Vtg);
  attn_k<<<dim3(32, 32), 256, 0, stream>>>(Qb, Kb, Vtg, AO);
  gemm_out<<<dim3(32, 16), 256, 0, stream>>>(AO, wob, out);
}